// Round 1
// baseline (408.395 us; speedup 1.0000x reference)
//
#include <hip/hip_runtime.h>
#include <hip/hip_bf16.h>

// Problem dims
#define B_ 64
#define L_ 12
#define N_ 883
#define D_ 64
#define T_ 12
#define M_ 64
#define NTILES 14            // ceil(883/64)

typedef __bf16 bf16x8 __attribute__((ext_vector_type(8)));
typedef __bf16 bf16x4 __attribute__((ext_vector_type(4)));
typedef float  f32x4  __attribute__((ext_vector_type(4)));

// ---------------------------------------------------------------------------
// Prep: M fp32 (12,64,64) -> Mh/Ml bf16 [t][m][d]  and  Mth bf16 [t][d][m]
// ---------------------------------------------------------------------------
__global__ __launch_bounds__(256) void prep_M(const float* __restrict__ M,
                                              __bf16* __restrict__ Mh,
                                              __bf16* __restrict__ Ml,
                                              __bf16* __restrict__ Mth) {
    int idx = blockIdx.x * 256 + threadIdx.x;
    if (idx >= T_ * M_ * D_) return;
    float v = M[idx];
    __bf16 h = (__bf16)v;
    __bf16 l = (__bf16)(v - (float)h);
    Mh[idx] = h;
    Ml[idx] = l;
    int t = idx >> 12;
    int m = (idx >> 6) & 63;
    int d = idx & 63;
    Mth[(t << 12) + (d << 6) + m] = h;
}

// ---------------------------------------------------------------------------
// Fused: xs = sum_l x ; logits = xs@M^T (hi/lo split, 3 MFMAs) ; softmax ;
//        value = P@M ; store.  One block = (b, tile of 64 n-rows), 4 waves.
// ---------------------------------------------------------------------------
__global__ __launch_bounds__(256, 4) void fused_kernel(
        const float* __restrict__ x,
        const __bf16* __restrict__ Mh,
        const __bf16* __restrict__ Ml,
        const __bf16* __restrict__ Mth,
        float* __restrict__ out) {
    // LDS: xs hi/lo (padded stride 72 for conflict-free ds_read_b128),
    // pbf is per-wave private -> no barriers inside the t-loop.
    __shared__ __bf16 xsh[64][72];
    __shared__ __bf16 xsl[64][72];
    __shared__ __bf16 pbf[4][16][72];

    const int tid  = threadIdx.x;
    const int lane = tid & 63;
    const int wave = tid >> 6;
    const int l15  = lane & 15;
    const int quad = lane >> 4;

    const int b  = blockIdx.x / NTILES;
    const int nt = blockIdx.x % NTILES;
    const int n0 = nt * 64;

    // ---- Phase A: stage xs = sum_l x[b,l,n0:n0+64,:] into LDS (hi/lo bf16)
    {
        const int r0 = tid >> 4;   // 0..15
        const int c4 = tid & 15;   // float4 column
        f32x4 acc[4];
        #pragma unroll
        for (int p = 0; p < 4; ++p) acc[p] = f32x4{0.f, 0.f, 0.f, 0.f};

        const float* xb = x + (size_t)b * (L_ * N_ * D_);
        for (int l = 0; l < L_; ++l) {
            const float* xl_ = xb + (size_t)l * (N_ * D_);
            #pragma unroll
            for (int p = 0; p < 4; ++p) {
                int row = p * 16 + r0;
                int n   = n0 + row;
                if (n < N_) {
                    f32x4 v = *(const f32x4*)(xl_ + (size_t)n * D_ + c4 * 4);
                    acc[p] += v;
                }
            }
        }
        #pragma unroll
        for (int p = 0; p < 4; ++p) {
            int row = p * 16 + r0;
            bf16x4 h4, l4;
            #pragma unroll
            for (int i = 0; i < 4; ++i) {
                float v = acc[p][i];
                __bf16 h = (__bf16)v;
                h4[i] = h;
                l4[i] = (__bf16)(v - (float)h);
            }
            *(bf16x4*)&xsh[row][c4 * 4] = h4;
            *(bf16x4*)&xsl[row][c4 * 4] = l4;
        }
    }
    __syncthreads();

    // ---- A-fragments for GEMM1 (constant across t): row = wave*16 + l15
    const int arow = wave * 16 + l15;
    bf16x8 a_h[2], a_l[2];
    #pragma unroll
    for (int kc = 0; kc < 2; ++kc) {
        a_h[kc] = *(const bf16x8*)&xsh[arow][kc * 32 + quad * 8];
        a_l[kc] = *(const bf16x8*)&xsl[arow][kc * 32 + quad * 8];
    }

    // ---- t-loop
    for (int t = 0; t < T_; ++t) {
        const __bf16* mh  = Mh  + (t << 12);
        const __bf16* ml  = Ml  + (t << 12);
        const __bf16* mth = Mth + (t << 12);

        // GEMM1: logits[n][m], hi/lo split (3 MFMAs per k-chunk)
        f32x4 c1[4];
        #pragma unroll
        for (int mt = 0; mt < 4; ++mt) c1[mt] = f32x4{0.f, 0.f, 0.f, 0.f};
        #pragma unroll
        for (int mt = 0; mt < 4; ++mt) {
            #pragma unroll
            for (int kc = 0; kc < 2; ++kc) {
                // B[k=d][col=m] = M[m][d]: lane reads row (mt*16+l15), 8 d's
                const __bf16* bp = mh + (size_t)(mt * 16 + l15) * 64 + kc * 32 + quad * 8;
                const __bf16* lp = ml + (size_t)(mt * 16 + l15) * 64 + kc * 32 + quad * 8;
                bf16x8 bh = *(const bf16x8*)bp;
                bf16x8 bl = *(const bf16x8*)lp;
                c1[mt] = __builtin_amdgcn_mfma_f32_16x16x32_bf16(a_h[kc], bh, c1[mt], 0, 0, 0);
                c1[mt] = __builtin_amdgcn_mfma_f32_16x16x32_bf16(a_l[kc], bh, c1[mt], 0, 0, 0);
                c1[mt] = __builtin_amdgcn_mfma_f32_16x16x32_bf16(a_h[kc], bl, c1[mt], 0, 0, 0);
            }
        }

        // Softmax over m (64) per row. Lane holds logits[row=quad*4+r][m=mt*16+l15].
        // Row-reduce = 4 regs (mt) in-lane + 16 lanes of the quad (xor 1,2,4,8).
        #pragma unroll
        for (int r = 0; r < 4; ++r) {
            float mx = fmaxf(fmaxf(c1[0][r], c1[1][r]), fmaxf(c1[2][r], c1[3][r]));
            #pragma unroll
            for (int off = 1; off < 16; off <<= 1)
                mx = fmaxf(mx, __shfl_xor(mx, off));
            float e[4];
            float s = 0.f;
            #pragma unroll
            for (int mt = 0; mt < 4; ++mt) {
                e[mt] = __expf(c1[mt][r] - mx);
                s += e[mt];
            }
            #pragma unroll
            for (int off = 1; off < 16; off <<= 1)
                s += __shfl_xor(s, off);
            float inv = 1.0f / s;
            #pragma unroll
            for (int mt = 0; mt < 4; ++mt)
                pbf[wave][quad * 4 + r][mt * 16 + l15] = (__bf16)(e[mt] * inv);
        }
        // pbf written/read by the SAME wave only -> in-order LDS, no barrier.

        // GEMM2: value[n][d] = P @ M[t]
        bf16x8 pa[2];
        #pragma unroll
        for (int kc = 0; kc < 2; ++kc)
            pa[kc] = *(const bf16x8*)&pbf[wave][l15][kc * 32 + quad * 8];

        f32x4 c2[4];
        #pragma unroll
        for (int dt = 0; dt < 4; ++dt) c2[dt] = f32x4{0.f, 0.f, 0.f, 0.f};
        #pragma unroll
        for (int dt = 0; dt < 4; ++dt) {
            #pragma unroll
            for (int kc = 0; kc < 2; ++kc) {
                // B[k=m][col=d] = M[m][d] = Mth[d][m]: lane reads row (dt*16+l15), 8 m's
                const __bf16* bp = mth + (size_t)(dt * 16 + l15) * 64 + kc * 32 + quad * 8;
                bf16x8 bv = *(const bf16x8*)bp;
                c2[dt] = __builtin_amdgcn_mfma_f32_16x16x32_bf16(pa[kc], bv, c2[dt], 0, 0, 0);
            }
        }

        // Store: c2[dt][r] = value[n = wave*16+quad*4+r][d = dt*16+l15]
        float* op = out + ((size_t)(b * T_ + t) * N_ + n0) * D_;
        #pragma unroll
        for (int dt = 0; dt < 4; ++dt) {
            #pragma unroll
            for (int r = 0; r < 4; ++r) {
                int row = wave * 16 + quad * 4 + r;
                if (n0 + row < N_)
                    op[(size_t)row * D_ + dt * 16 + l15] = c2[dt][r];
            }
        }
    }
}

// ---------------------------------------------------------------------------
extern "C" void kernel_launch(void* const* d_in, const int* in_sizes, int n_in,
                              void* d_out, int out_size, void* d_ws, size_t ws_size,
                              hipStream_t stream) {
    const float* x = (const float*)d_in[0];
    const float* M = (const float*)d_in[1];
    float* out = (float*)d_out;

    __bf16* Mh  = (__bf16*)d_ws;                 // 12*64*64 bf16 = 96 KiB
    __bf16* Ml  = Mh + T_ * M_ * D_;
    __bf16* Mth = Ml + T_ * M_ * D_;             // total 288 KiB of ws

    prep_M<<<(T_ * M_ * D_ + 255) / 256, 256, 0, stream>>>(M, Mh, Ml, Mth);
    fused_kernel<<<B_ * NTILES, 256, 0, stream>>>(x, Mh, Ml, Mth, out);
}

// Round 2
// 403.562 us; speedup vs baseline: 1.0120x; 1.0120x over previous
//
#include <hip/hip_runtime.h>
#include <hip/hip_bf16.h>

// Problem dims
#define B_ 64
#define L_ 12
#define N_ 883
#define D_ 64
#define T_ 12
#define M_ 64
#define NTILES 14            // ceil(883/64)
#define TSPLIT 4             // t-groups; 3 t per block

typedef __bf16 bf16x8 __attribute__((ext_vector_type(8)));
typedef __bf16 bf16x4 __attribute__((ext_vector_type(4)));
typedef float  f32x4  __attribute__((ext_vector_type(4)));

// ---------------------------------------------------------------------------
// Prep: M fp32 (12,64,64) -> Mh/Ml bf16 [t][m][d]  and  Mth bf16 [t][d][m]
// ---------------------------------------------------------------------------
__global__ __launch_bounds__(256) void prep_M(const float* __restrict__ M,
                                              __bf16* __restrict__ Mh,
                                              __bf16* __restrict__ Ml,
                                              __bf16* __restrict__ Mth) {
    int idx = blockIdx.x * 256 + threadIdx.x;
    if (idx >= T_ * M_ * D_) return;
    float v = M[idx];
    __bf16 h = (__bf16)v;
    __bf16 l = (__bf16)(v - (float)h);
    Mh[idx] = h;
    Ml[idx] = l;
    int t = idx >> 12;
    int m = (idx >> 6) & 63;
    int d = idx & 63;
    Mth[(t << 12) + (d << 6) + m] = h;
}

// ---------------------------------------------------------------------------
// xs[b,n,d] = sum_l x[b,l,n,d].  Streaming reduce: 173.6 MB -> 14.5 MB.
// One thread per float4 of output.
// ---------------------------------------------------------------------------
__global__ __launch_bounds__(256) void xs_reduce(const float* __restrict__ x,
                                                 float* __restrict__ xs) {
    const size_t total = (size_t)B_ * N_ * 16;     // float4 count = 904192
    size_t idx = (size_t)blockIdx.x * 256 + threadIdx.x;
    if (idx >= total) return;
    size_t b   = idx / (N_ * 16);
    size_t rem = idx - b * (N_ * 16);              // n*16 + c4
    const f32x4* xp = (const f32x4*)x + b * (size_t)(L_ * N_ * 16) + rem;
    f32x4 s = f32x4{0.f, 0.f, 0.f, 0.f};
    #pragma unroll
    for (int l = 0; l < L_; ++l)
        s += xp[(size_t)l * (N_ * 16)];
    ((f32x4*)xs)[idx] = s;
}

// ---------------------------------------------------------------------------
// Attention: per (b, n-tile, t-group of 3): stage xs tile (hi/lo bf16) in LDS,
// then logits = xs@M^T (hi/lo, 3 MFMAs), softmax over m, value = P@M, store.
// ---------------------------------------------------------------------------
__global__ __launch_bounds__(256, 5) void fused_attn(
        const float* __restrict__ xs,
        const __bf16* __restrict__ Mh,
        const __bf16* __restrict__ Ml,
        const __bf16* __restrict__ Mth,
        float* __restrict__ out) {
    __shared__ __bf16 xsh[64][72];
    __shared__ __bf16 xsl[64][72];
    __shared__ __bf16 pbf[4][16][72];   // per-wave private P staging

    const int tid  = threadIdx.x;
    const int lane = tid & 63;
    const int wave = tid >> 6;
    const int l15  = lane & 15;
    const int quad = lane >> 4;

    const int t0 = blockIdx.x * (T_ / TSPLIT);   // 3 t's per block
    const int nt = blockIdx.y;
    const int b  = blockIdx.z;
    const int n0 = nt * 64;

    // ---- Stage xs tile (fp32 from L2/L3) -> hi/lo bf16 in LDS
    {
        const int r0 = tid >> 4;   // 0..15
        const int c4 = tid & 15;   // float4 column
        #pragma unroll
        for (int p = 0; p < 4; ++p) {
            int row = p * 16 + r0;
            int n   = n0 + row;
            f32x4 v = f32x4{0.f, 0.f, 0.f, 0.f};
            if (n < N_)
                v = *(const f32x4*)(xs + ((size_t)b * N_ + n) * D_ + c4 * 4);
            bf16x4 h4, l4;
            #pragma unroll
            for (int i = 0; i < 4; ++i) {
                __bf16 h = (__bf16)v[i];
                h4[i] = h;
                l4[i] = (__bf16)(v[i] - (float)h);
            }
            *(bf16x4*)&xsh[row][c4 * 4] = h4;
            *(bf16x4*)&xsl[row][c4 * 4] = l4;
        }
    }
    __syncthreads();

    // ---- A-fragments for GEMM1 (constant across t): row = wave*16 + l15
    const int arow = wave * 16 + l15;
    bf16x8 a_h[2], a_l[2];
    #pragma unroll
    for (int kc = 0; kc < 2; ++kc) {
        a_h[kc] = *(const bf16x8*)&xsh[arow][kc * 32 + quad * 8];
        a_l[kc] = *(const bf16x8*)&xsl[arow][kc * 32 + quad * 8];
    }

    // ---- t-loop (3 iterations)
    #pragma unroll
    for (int ti = 0; ti < T_ / TSPLIT; ++ti) {
        const int t = t0 + ti;
        const __bf16* mh  = Mh  + (t << 12);
        const __bf16* ml  = Ml  + (t << 12);
        const __bf16* mth = Mth + (t << 12);

        // GEMM1: logits[n][m], hi/lo split (3 MFMAs per k-chunk)
        f32x4 c1[4];
        #pragma unroll
        for (int mt = 0; mt < 4; ++mt) c1[mt] = f32x4{0.f, 0.f, 0.f, 0.f};
        #pragma unroll
        for (int mt = 0; mt < 4; ++mt) {
            #pragma unroll
            for (int kc = 0; kc < 2; ++kc) {
                const __bf16* bp = mh + (size_t)(mt * 16 + l15) * 64 + kc * 32 + quad * 8;
                const __bf16* lp = ml + (size_t)(mt * 16 + l15) * 64 + kc * 32 + quad * 8;
                bf16x8 bh = *(const bf16x8*)bp;
                bf16x8 bl = *(const bf16x8*)lp;
                c1[mt] = __builtin_amdgcn_mfma_f32_16x16x32_bf16(a_h[kc], bh, c1[mt], 0, 0, 0);
                c1[mt] = __builtin_amdgcn_mfma_f32_16x16x32_bf16(a_l[kc], bh, c1[mt], 0, 0, 0);
                c1[mt] = __builtin_amdgcn_mfma_f32_16x16x32_bf16(a_h[kc], bl, c1[mt], 0, 0, 0);
            }
        }

        // Softmax over m (64) per row; lane holds logits[quad*4+r][mt*16+l15].
        #pragma unroll
        for (int r = 0; r < 4; ++r) {
            float mx = fmaxf(fmaxf(c1[0][r], c1[1][r]), fmaxf(c1[2][r], c1[3][r]));
            #pragma unroll
            for (int off = 1; off < 16; off <<= 1)
                mx = fmaxf(mx, __shfl_xor(mx, off));
            float e[4];
            float s = 0.f;
            #pragma unroll
            for (int mt = 0; mt < 4; ++mt) {
                e[mt] = __expf(c1[mt][r] - mx);
                s += e[mt];
            }
            #pragma unroll
            for (int off = 1; off < 16; off <<= 1)
                s += __shfl_xor(s, off);
            float inv = 1.0f / s;
            #pragma unroll
            for (int mt = 0; mt < 4; ++mt)
                pbf[wave][quad * 4 + r][mt * 16 + l15] = (__bf16)(e[mt] * inv);
        }
        // pbf written/read by the SAME wave only -> in-order LDS, no barrier.

        // GEMM2: value[n][d] = P @ M[t]
        bf16x8 pa[2];
        #pragma unroll
        for (int kc = 0; kc < 2; ++kc)
            pa[kc] = *(const bf16x8*)&pbf[wave][l15][kc * 32 + quad * 8];

        f32x4 c2[4];
        #pragma unroll
        for (int dt = 0; dt < 4; ++dt) c2[dt] = f32x4{0.f, 0.f, 0.f, 0.f};
        #pragma unroll
        for (int dt = 0; dt < 4; ++dt) {
            #pragma unroll
            for (int kc = 0; kc < 2; ++kc) {
                const __bf16* bp = mth + (size_t)(dt * 16 + l15) * 64 + kc * 32 + quad * 8;
                bf16x8 bv = *(const bf16x8*)bp;
                c2[dt] = __builtin_amdgcn_mfma_f32_16x16x32_bf16(pa[kc], bv, c2[dt], 0, 0, 0);
            }
        }

        // Store: c2[dt][r] = value[n = wave*16+quad*4+r][d = dt*16+l15]
        float* op = out + ((size_t)(b * T_ + t) * N_ + n0) * D_;
        #pragma unroll
        for (int dt = 0; dt < 4; ++dt) {
            #pragma unroll
            for (int r = 0; r < 4; ++r) {
                int row = wave * 16 + quad * 4 + r;
                if (n0 + row < N_)
                    op[(size_t)row * D_ + dt * 16 + l15] = c2[dt][r];
            }
        }
    }
}

// ---------------------------------------------------------------------------
extern "C" void kernel_launch(void* const* d_in, const int* in_sizes, int n_in,
                              void* d_out, int out_size, void* d_ws, size_t ws_size,
                              hipStream_t stream) {
    const float* x = (const float*)d_in[0];
    const float* M = (const float*)d_in[1];
    float* out = (float*)d_out;

    __bf16* Mh  = (__bf16*)d_ws;                 // 12*64*64 bf16 = 96 KiB
    __bf16* Ml  = Mh + T_ * M_ * D_;
    __bf16* Mth = Ml + T_ * M_ * D_;
    float*  xs  = (float*)((char*)d_ws + 3 * (size_t)T_ * M_ * D_ * 2); // 14.5 MB

    prep_M<<<(T_ * M_ * D_ + 255) / 256, 256, 0, stream>>>(M, Mh, Ml, Mth);

    const size_t xs_f4 = (size_t)B_ * N_ * 16;
    xs_reduce<<<(int)((xs_f4 + 255) / 256), 256, 0, stream>>>(x, xs);

    fused_attn<<<dim3(TSPLIT, NTILES, B_), 256, 0, stream>>>(xs, Mh, Ml, Mth, out);
}